// Round 13
// baseline (4947.387 us; speedup 1.0000x reference)
//
#include <hip/hip_runtime.h>
#include <cstdint>

// ---------------------------------------------------------------------------
// Threefry-2x32 (JAX partitionable-mode compatible), host + device.
// ---------------------------------------------------------------------------
__host__ __device__ inline uint32_t tf_rotl32(uint32_t x, uint32_t r) {
  return (x << r) | (x >> (32u - r));
}

__host__ __device__ inline void threefry2x32(uint32_t k0, uint32_t k1,
                                             uint32_t x0, uint32_t x1,
                                             uint32_t* o0, uint32_t* o1) {
  uint32_t ks0 = k0, ks1 = k1, ks2 = k0 ^ k1 ^ 0x1BD11BDAu;
  x0 += ks0; x1 += ks1;
#define TF_R(r) { x0 += x1; x1 = tf_rotl32(x1, r); x1 ^= x0; }
  TF_R(13) TF_R(15) TF_R(26) TF_R(6)
  x0 += ks1; x1 += ks2 + 1u;
  TF_R(17) TF_R(29) TF_R(16) TF_R(24)
  x0 += ks2; x1 += ks0 + 2u;
  TF_R(13) TF_R(15) TF_R(26) TF_R(6)
  x0 += ks0; x1 += ks1 + 3u;
  TF_R(17) TF_R(29) TF_R(16) TF_R(24)
  x0 += ks1; x1 += ks2 + 4u;
  TF_R(13) TF_R(15) TF_R(26) TF_R(6)
  x0 += ks2; x1 += ks0 + 5u;
#undef TF_R
  *o0 = x0; *o1 = x1;
}

// ---------------------------------------------------------------------------
// Problem dims
// ---------------------------------------------------------------------------
#define BSZ   8192
#define KIN   784
#define HID   800
#define NOUT  10
#define NSTEP 25

// R8: golden = Eigen gebp (AVX no-FMA jaxlib): k-panels [0,264) [264,528)
// [528,784), per k-step acc = rn(acc + rn(a*b)); C = 0.5*rn(rn(P0+P1)+P2).
// R9: a in {0,1,2} makes every product exact, so fmaf == mul+add bit-exactly.
// R17: panel-split grid x3 -> occ 72%, gemm 158us.
// R20/R21 nulls: staging removal, register prefetch -> wall invariant 157us,
//   both pipes ~78%. Budget: VALU ~122us, LDS ~124us (10 b128/tile-thread),
//   wall = max-pipe x ~1.27 stall factor. Must SHRINK a pipe.
// R22 (this round): 8x4 per thread at 128 threads/block, BM=128 — block
//   count STAYS 4800 (the variable that killed R3/R4/R8/R10 was blocks,
//   not shape). Per tile-thread: A=4xb128 (8 rows contiguous) + B=8xb128
//   = 12 instr per 256 MACs (21.3 MACs/instr vs 12.8) -> LDS ~74us,
//   VALU ~100us. A staging groups padded (68-word stride) so the 4-group
//   b128 reads spread all 32 banks at 2-way (free); gload_lds dest stays
//   linear within each instruction. Predict gemm 157 -> 120-140us;
//   falsifier >=150 -> barrier-cadence is the last lever.
// ---------------------------------------------------------------------------

// ---------------------------------------------------------------------------
// Kernel 1: Poisson encoding (JAX-faithful: truncated 2^-23 grid).
// enc = temp + 1 in {0,1,2}; sp = 0.5*enc (exact power-of-2 relation).
// ---------------------------------------------------------------------------
__global__ __launch_bounds__(256) void enc_kernel(const float* __restrict__ inp,
                                                  uint8_t* __restrict__ enc,
                                                  uint32_t k0, uint32_t k1) {
  int j = blockIdx.x * blockDim.x + threadIdx.x;
  if (j >= BSZ * KIN) return;
  uint32_t o0, o1;
  threefry2x32(k0, k1, 0u, (uint32_t)j, &o0, &o1);
  uint32_t bits = o0 ^ o1;
  float r = __uint_as_float((bits >> 9) | 0x3f800000u) - 1.0f;
  float x = inp[j];
  bool cond = (2.0f * r <= fabsf(x));
  int s = (x > 0.0f) ? 1 : ((x < 0.0f) ? -1 : 0);
  enc[j] = (uint8_t)(1 + (cond ? s : 0));
}

// ---------------------------------------------------------------------------
// Kernel 2: panel partial Pz[b,j] for panel z = blockIdx.z.
// BM=128, BN=32, BK=8. 128 threads (2 waves), 8x4 acc per thread.
// As: u8 row-major, 4 staging groups of 32 rows, group stride 68 words
//     (4-word pad between groups -> A-frag b128 reads 2-way on banks, free).
//     Row r: group g=r/32, words 68g + (r%32)*2 .. +1  (k0-3, k4-7).
// Bs: f32 [BK][BN] via transpose-by-address gload_lds (wave1).
// Inner per tile/thread: 4x b128 (A, 8 rows) + 8x b128 (B) + per kk:
// 8 cvt + 16 pk_fma.
// ---------------------------------------------------------------------------
#define BM 128
#define BN 32
#define BK 8
#define AGRP 68                    // words per 32-row staging group (64+4 pad)
#define ASZ  (3 * AGRP + 64)       // 268 words per buffer

typedef float f32x2 __attribute__((ext_vector_type(2)));
typedef uint32_t u32;

__device__ __forceinline__ float cvt_ub(u32 x, int i) {
  return (float)((x >> (8 * i)) & 0xffu);   // folds to v_cvt_f32_ubyte_i
}

// async global->LDS, 4B/lane: LDS dest = base + lane*4; source per-lane.
__device__ __forceinline__ void gload4(const void* g, void* l) {
  __builtin_amdgcn_global_load_lds(
      (const __attribute__((address_space(1))) void*)g,
      (__attribute__((address_space(3))) void*)l, 4, 0, 0);
}

// acc.lo = fma(a.lo, b.lo, acc.lo); acc.hi = fma(a.lo, b.hi, acc.hi)
// Per-half rounding == v_fma_f32 (bit-exact); src0 half broadcast via op_sel.
__device__ __forceinline__ void pk_fma_lo(f32x2& acc, f32x2 a, f32x2 b) {
  asm("v_pk_fma_f32 %0, %1, %2, %0 op_sel:[0,0,0] op_sel_hi:[0,1,1]"
      : "+v"(acc)
      : "v"(a), "v"(b));
}
// same but broadcasting src0.hi
__device__ __forceinline__ void pk_fma_hi(f32x2& acc, f32x2 a, f32x2 b) {
  asm("v_pk_fma_f32 %0, %1, %2, %0 op_sel:[1,0,0] op_sel_hi:[1,1,1]"
      : "+v"(acc)
      : "v"(a), "v"(b));
}

__global__ __launch_bounds__(128) void gemm_kernel(const uint8_t* __restrict__ enc,
                                                   const float* __restrict__ w1,
                                                   float* __restrict__ gp) {
  __shared__ u32   As[2][ASZ];          // 2 x ~1.05 KB
  __shared__ float Bs[2][BK][BN];       // 2 x 1 KB
  const int panel  = blockIdx.z;
  const int kstart = panel * 264;
  const int ntile  = (panel == 2) ? 32 : 33;
  const int m0 = blockIdx.x * BM;
  const int n0 = blockIdx.y * BN;
  const int t  = threadIdx.x;
  const int lane = t & 63;
  const int wv   = t >> 6;

  // compute mapping: 16 row-groups (8 rows each) x 8 col-groups (4 cols)
  const int tm = t / 8;        // 0..15 -> rows tm*8 .. +7
  const int tn = t % 8;        // 0..7  -> cols tn*4 .. +3

  // per-lane staging source bases (k-offset 0 of this panel)
  // A instr q, lane i -> LDS word 68q+i = row 32q+(i>>1), k-half (i&1)
  const uint8_t* a_src = enc + (size_t)(m0 + (lane >> 1)) * KIN + kstart + (lane & 1) * 4;
  // B instr q, lane i -> LDS word 64q+i = Bs[2q+(i>>5)][i&31]
  const float*   b_src = w1  + (size_t)(n0 + (lane & 31)) * KIN + kstart + (lane >> 5);

  f32x2 acc[8][2];   // single panel chain: [mi][nj] covers cols 2nj,2nj+1
#pragma unroll
  for (int mi = 0; mi < 8; mi++)
#pragma unroll
    for (int nj = 0; nj < 2; nj++) acc[mi][nj] = (f32x2)(0.0f);

#define ISSUE(P, TILE)                                                    \
  {                                                                       \
    if (wv == 0) {                                                        \
      _Pragma("unroll")                                                   \
      for (int q = 0; q < 4; q++)                                         \
        gload4(a_src + (size_t)(TILE) * BK + (size_t)(32 * q) * KIN,      \
               &As[P][AGRP * q]);                                         \
    } else {                                                              \
      _Pragma("unroll")                                                   \
      for (int q = 0; q < 4; q++)                                         \
        gload4(b_src + (size_t)(TILE) * BK + 2 * q, &Bs[P][2 * q][0]);    \
    }                                                                     \
  }

  // ---- prologue: stage tile 0 into buffer 0 ----
  ISSUE(0, 0)
  __syncthreads();   // issuing waves drain vmcnt before signaling

  // A-frag base: rows 8tm..8tm+7 = 16 contiguous words inside group tm/4
  const int afrag = AGRP * (tm >> 2) + 16 * (tm & 3);

  int p = 0;
  for (int tile = 0; tile < ntile; tile++) {
    // issue next tile into the other buffer; lands while we compute
    if (tile + 1 < ntile) { ISSUE(p ^ 1, tile + 1) }
    // ---- A fragment: 8 rows x 8 kk = 64 B = 4x ds_read_b128 ----
    const u32* aw = &As[p][afrag];
    uint4 q0 = *(const uint4*)(aw);       // rows 8tm+0,1
    uint4 q1 = *(const uint4*)(aw + 4);   // rows 8tm+2,3
    uint4 q2 = *(const uint4*)(aw + 8);   // rows 8tm+4,5
    uint4 q3 = *(const uint4*)(aw + 12);  // rows 8tm+6,7
#pragma unroll
    for (int kk = 0; kk < BK; kk++) {
      const int sh = kk & 3;
      const u32 r0 = (kk < 4) ? q0.x : q0.y;   // row 8tm+0
      const u32 r1 = (kk < 4) ? q0.z : q0.w;   // row 8tm+1
      const u32 r2 = (kk < 4) ? q1.x : q1.y;   // row 8tm+2
      const u32 r3 = (kk < 4) ? q1.z : q1.w;   // row 8tm+3
      const u32 r4 = (kk < 4) ? q2.x : q2.y;   // row 8tm+4
      const u32 r5 = (kk < 4) ? q2.z : q2.w;   // row 8tm+5
      const u32 r6 = (kk < 4) ? q3.x : q3.y;   // row 8tm+6
      const u32 r7 = (kk < 4) ? q3.z : q3.w;   // row 8tm+7
      f32x2 am[4];
      am[0].x = cvt_ub(r0, sh);  am[0].y = cvt_ub(r1, sh);
      am[1].x = cvt_ub(r2, sh);  am[1].y = cvt_ub(r3, sh);
      am[2].x = cvt_ub(r4, sh);  am[2].y = cvt_ub(r5, sh);
      am[3].x = cvt_ub(r6, sh);  am[3].y = cvt_ub(r7, sh);
      float4 bv = *(const float4*)&Bs[p][kk][tn * 4];
      f32x2 b2[2];
      b2[0].x = bv.x; b2[0].y = bv.y;
      b2[1].x = bv.z; b2[1].y = bv.w;
      // rows: mi = 2*mp + h (h = broadcast half of am[mp]); ascending-k chain
#pragma unroll
      for (int mp = 0; mp < 4; mp++) {
        pk_fma_lo(acc[2 * mp + 0][0], am[mp], b2[0]);
        pk_fma_lo(acc[2 * mp + 0][1], am[mp], b2[1]);
        pk_fma_hi(acc[2 * mp + 1][0], am[mp], b2[0]);
        pk_fma_hi(acc[2 * mp + 1][1], am[mp], b2[1]);
      }
    }
    __syncthreads();   // everyone done reading p; next-tile loads landed
    p ^= 1;
  }
#undef ISSUE

  // epilogue: write RAW panel partial (combine happens in update_kernel)
  float* base = gp + (size_t)panel * BSZ * HID;
#pragma unroll
  for (int mi = 0; mi < 8; mi++) {
    float* dst = base + (size_t)(m0 + tm * 8 + mi) * HID + n0 + tn * 4;
    float4 o;
    o.x = acc[mi][0].x;
    o.y = acc[mi][0].y;
    o.z = acc[mi][1].x;
    o.w = acc[mi][1].y;
    *(float4*)dst = o;
  }
}

// ---------------------------------------------------------------------------
// Kernel 3: combine panels (exact Eigen order) + membrane update + spike +
// mem2 accumulation.
// g = 0.5 * rn(rn(P0+P1) + P2)   (0.5 exact)
// m = rn(rn(0.95f*mem) + rn(0.05f*g)) — mul/mul/add; products NOT exact here,
// so FMA contraction would change bits — keep split __fmul_rn/__fadd_rn.
// ---------------------------------------------------------------------------
__global__ __launch_bounds__(256) void update_kernel(const float* __restrict__ gp,
                                                     float* __restrict__ mem1,
                                                     const float* __restrict__ w2,
                                                     float* __restrict__ mem2) {
  __shared__ float w2s[NOUT * HID];   // 32 KB
  for (int i = threadIdx.x; i < NOUT * HID; i += 256) w2s[i] = w2[i];
  __syncthreads();

  const int wave = threadIdx.x / 64;
  const int lane = threadIdx.x % 64;
  const int b = blockIdx.x * 4 + wave;

  const size_t GS = (size_t)BSZ * HID;
  const float* g0 = gp + (size_t)b * HID;
  const float* g1 = g0 + GS;
  const float* g2 = g1 + GS;
  float* mrow = mem1 + (size_t)b * HID;

  float acc[NOUT];
#pragma unroll
  for (int i = 0; i < NOUT; i++) acc[i] = 0.0f;

  for (int j = lane; j < HID; j += 64) {
    float gs = __fmul_rn(0.5f, __fadd_rn(__fadd_rn(g0[j], g1[j]), g2[j]));
    float m = __fadd_rn(__fmul_rn(0.95f, mrow[j]), __fmul_rn(0.05f, gs));
    bool spike = __fadd_rn(m, -1.0f) > 0.0f;
    mrow[j] = spike ? __fadd_rn(m, -1.0f) : m;
    if (spike) {
#pragma unroll
      for (int i = 0; i < NOUT; i++) acc[i] += w2s[i * HID + j];
    }
  }
  // mem2 never feeds back into spike decisions: reduction-order noise ~1e-7
  // << 3.6e-3 threshold, no need to replicate ref's order here.
#pragma unroll
  for (int i = 0; i < NOUT; i++) {
    float v = acc[i];
    for (int off = 32; off > 0; off >>= 1) v += __shfl_down(v, off);
    if (lane == 0) mem2[(size_t)b * NOUT + i] += v;
  }
}

// ---------------------------------------------------------------------------
// Kernel 4: out = mem2 / num_steps
// ---------------------------------------------------------------------------
__global__ __launch_bounds__(256) void finalize_kernel(const float* __restrict__ mem2,
                                                       const int* __restrict__ ns,
                                                       float* __restrict__ out) {
  int i = blockIdx.x * blockDim.x + threadIdx.x;
  if (i < BSZ * NOUT) out[i] = mem2[i] / (float)(*ns);
}

// ---------------------------------------------------------------------------
extern "C" void kernel_launch(void* const* d_in, const int* in_sizes, int n_in,
                              void* d_out, int out_size, void* d_ws, size_t ws_size,
                              hipStream_t stream) {
  const float* inp = (const float*)d_in[0];
  const float* w1  = (const float*)d_in[1];
  const float* w2  = (const float*)d_in[2];
  const int*   dns = (const int*)d_in[3];
  float* out = (float*)d_out;

  char* ws = (char*)d_ws;
  size_t off = 0;
  uint8_t* enc = (uint8_t*)(ws + off);  off += (size_t)BSZ * KIN;          // 6.4 MB
  off = (off + 255) & ~(size_t)255;
  float* gp   = (float*)(ws + off);     off += (size_t)3 * BSZ * HID * 4;  // 78.6 MB
  float* mem1 = (float*)(ws + off);     off += (size_t)BSZ * HID * 4;      // 26.2 MB
  float* mem2 = (float*)(ws + off);     off += (size_t)BSZ * NOUT * 4;     // 0.33 MB

  (void)hipMemsetAsync(mem1, 0, (size_t)BSZ * HID * 4, stream);
  (void)hipMemsetAsync(mem2, 0, (size_t)BSZ * NOUT * 4, stream);

  // Step keys: partitionable split — key_t = threefry((0,42), (0,t)).
  uint32_t keys[NSTEP][2];
  for (int t = 0; t < NSTEP; t++)
    threefry2x32(0u, 42u, 0u, (uint32_t)t, &keys[t][0], &keys[t][1]);

  const int n_elem = BSZ * KIN;
  for (int t = 0; t < NSTEP; t++) {
    enc_kernel<<<(n_elem + 255) / 256, 256, 0, stream>>>(inp, enc, keys[t][0], keys[t][1]);
    gemm_kernel<<<dim3(BSZ / BM, HID / BN, 3), 128, 0, stream>>>(enc, w1, gp);
    update_kernel<<<BSZ / 4, 256, 0, stream>>>(gp, mem1, w2, mem2);
  }
  finalize_kernel<<<(BSZ * NOUT + 255) / 256, 256, 0, stream>>>(mem2, dns, out);
}

// Round 14
// 4726.645 us; speedup vs baseline: 1.0467x; 1.0467x over previous
//
#include <hip/hip_runtime.h>
#include <cstdint>

// ---------------------------------------------------------------------------
// Threefry-2x32 (JAX partitionable-mode compatible), host + device.
// ---------------------------------------------------------------------------
__host__ __device__ inline uint32_t tf_rotl32(uint32_t x, uint32_t r) {
  return (x << r) | (x >> (32u - r));
}

__host__ __device__ inline void threefry2x32(uint32_t k0, uint32_t k1,
                                             uint32_t x0, uint32_t x1,
                                             uint32_t* o0, uint32_t* o1) {
  uint32_t ks0 = k0, ks1 = k1, ks2 = k0 ^ k1 ^ 0x1BD11BDAu;
  x0 += ks0; x1 += ks1;
#define TF_R(r) { x0 += x1; x1 = tf_rotl32(x1, r); x1 ^= x0; }
  TF_R(13) TF_R(15) TF_R(26) TF_R(6)
  x0 += ks1; x1 += ks2 + 1u;
  TF_R(17) TF_R(29) TF_R(16) TF_R(24)
  x0 += ks2; x1 += ks0 + 2u;
  TF_R(13) TF_R(15) TF_R(26) TF_R(6)
  x0 += ks0; x1 += ks1 + 3u;
  TF_R(17) TF_R(29) TF_R(16) TF_R(24)
  x0 += ks1; x1 += ks2 + 4u;
  TF_R(13) TF_R(15) TF_R(26) TF_R(6)
  x0 += ks2; x1 += ks0 + 5u;
#undef TF_R
  *o0 = x0; *o1 = x1;
}

// ---------------------------------------------------------------------------
// Problem dims
// ---------------------------------------------------------------------------
#define BSZ   8192
#define KIN   784
#define HID   800
#define NOUT  10
#define NSTEP 25

// R8: golden = Eigen gebp (AVX no-FMA jaxlib): k-panels [0,264) [264,528)
// [528,784), per k-step acc = rn(acc + rn(a*b)); C = 0.5*rn(rn(P0+P1)+P2).
// R9: a in {0,1,2} makes every product exact, so fmaf == mul+add bit-exactly.
// R17: panel-split grid x3 -> occ 72%, gemm 158us (best config).
// R20/R21/R22 nulls: staging-elim, reg-prefetch, tile reshape — wall pinned
//   at 157-165us. Budget: LDS 124us (10 b128/tile-thread, data-volume min),
//   VALU 122us; wall = max-pipe x 1.27 stall.
// R23 (this round): SINGLE variable — barrier count 33 -> 17 via BK=16.
//   (a) A frag bank fix: 4-row groups padded to 20-word stride -> frag b128
//       banks (20tm+4j)%32 all-distinct across tm; staging stays linear
//       (pad words written with garbage, never read); per-lane src offsets
//       (div 20) computed once, held as 10 u32.
//   (b) tail tiles (264 = 16x16+8): 17th tile full-16 with B kk8..15 staged
//       from a zeroed buffer. Bit-exact: a>=0 so a*(+0)=+0, acc never -0,
//       rn(acc + +0) = acc. A reads real data x0, in-bounds.
//   Predict gemm 157 -> 135-148 if barrier-bound; >=152 -> declare
//   structural roofline (max-pipe 124us floor, 4 failed attacks above it).
// ---------------------------------------------------------------------------

// ---------------------------------------------------------------------------
// Kernel 1: Poisson encoding (JAX-faithful: truncated 2^-23 grid).
// enc = temp + 1 in {0,1,2}; sp = 0.5*enc (exact power-of-2 relation).
// ---------------------------------------------------------------------------
__global__ __launch_bounds__(256) void enc_kernel(const float* __restrict__ inp,
                                                  uint8_t* __restrict__ enc,
                                                  uint32_t k0, uint32_t k1) {
  int j = blockIdx.x * blockDim.x + threadIdx.x;
  if (j >= BSZ * KIN) return;
  uint32_t o0, o1;
  threefry2x32(k0, k1, 0u, (uint32_t)j, &o0, &o1);
  uint32_t bits = o0 ^ o1;
  float r = __uint_as_float((bits >> 9) | 0x3f800000u) - 1.0f;
  float x = inp[j];
  bool cond = (2.0f * r <= fabsf(x));
  int s = (x > 0.0f) ? 1 : ((x < 0.0f) ? -1 : 0);
  enc[j] = (uint8_t)(1 + (cond ? s : 0));
}

// ---------------------------------------------------------------------------
// Kernel 2: panel partial Pz[b,j] for panel z = blockIdx.z.
// BM=128, BN=32, BK=16. 256 threads (4 waves), 4x4 acc per thread.
// As: u8, 32 groups of 4 rows, group stride 20 words (16 data + 4 pad).
//     Group g word layout: 4r' + wj = row 4g+r', k-bytes 4wj..4wj+3.
// Bs: f32 [BK][BN] via transpose-by-address gload_lds (wave1).
// Panels 0,1: 16 full tiles + 1 tail tile (B kk8..15 from zero buffer).
// ---------------------------------------------------------------------------
#define BM 128
#define BN 32
#define BK 16
#define AGW 20                     // words per 4-row group (16 data + 4 pad)
#define ASZ (32 * AGW)             // 640 words = 10 gload4 instrs exactly

typedef float f32x2 __attribute__((ext_vector_type(2)));
typedef uint32_t u32;

__device__ __forceinline__ float cvt_ub(u32 x, int i) {
  return (float)((x >> (8 * i)) & 0xffu);   // folds to v_cvt_f32_ubyte_i
}

// async global->LDS, 4B/lane: LDS dest = base + lane*4; source per-lane.
__device__ __forceinline__ void gload4(const void* g, void* l) {
  __builtin_amdgcn_global_load_lds(
      (const __attribute__((address_space(1))) void*)g,
      (__attribute__((address_space(3))) void*)l, 4, 0, 0);
}

// acc.lo = fma(a.lo, b.lo, acc.lo); acc.hi = fma(a.lo, b.hi, acc.hi)
// Per-half rounding == v_fma_f32 (bit-exact); src0 half broadcast via op_sel.
__device__ __forceinline__ void pk_fma_lo(f32x2& acc, f32x2 a, f32x2 b) {
  asm("v_pk_fma_f32 %0, %1, %2, %0 op_sel:[0,0,0] op_sel_hi:[0,1,1]"
      : "+v"(acc)
      : "v"(a), "v"(b));
}
// same but broadcasting src0.hi
__device__ __forceinline__ void pk_fma_hi(f32x2& acc, f32x2 a, f32x2 b) {
  asm("v_pk_fma_f32 %0, %1, %2, %0 op_sel:[1,0,0] op_sel_hi:[1,1,1]"
      : "+v"(acc)
      : "v"(a), "v"(b));
}

__global__ __launch_bounds__(256) void gemm_kernel(const uint8_t* __restrict__ enc,
                                                   const float* __restrict__ w1,
                                                   const float* __restrict__ zbuf,
                                                   float* __restrict__ gp) {
  __shared__ u32   As[2][ASZ];          // 2 x 2.5 KB
  __shared__ float Bs[2][BK][BN];       // 2 x 2 KB
  const int panel  = blockIdx.z;
  const int kstart = panel * 264;
  const bool htail = (panel != 2);
  const int ntile  = htail ? 17 : 16;   // panels 0,1: 16 full + 1 tail
  const int m0 = blockIdx.x * BM;
  const int n0 = blockIdx.y * BN;
  const int t  = threadIdx.x;
  const int lane = t & 63;
  const int wv   = t >> 6;

  // compute mapping: 32 row-groups x 8 col-groups, 4x4 per thread
  const int tm = t / 8;        // 0..31 -> rows tm*4 .. +3
  const int tn = t % 8;        // 0..7  -> cols tn*4 .. +3

  // ---- staging address setup ----
  // A (wave0): 10 instrs; instr q, lane i -> LDS word w = 64q+i.
  // w -> group g = w/20, rem = w%20; rem<16: row 4g+(rem>>2), kbyte (rem&3)*4;
  // rem>=16: pad (source = row 0, harmless).
  u32 aoff[10];
  if (wv == 0) {
#pragma unroll
    for (int q = 0; q < 10; q++) {
      const int w = 64 * q + lane;
      const int g = w / 20, rem = w % 20;
      aoff[q] = (rem < 16) ? (u32)((4 * g + (rem >> 2)) * KIN + (rem & 3) * 4)
                           : 0u;
    }
  }
  const uint8_t* a_base = enc + (size_t)m0 * KIN + kstart;
  // B (wave1): 8 instrs; instr q, lane i -> word 64q+i = Bs[2q+(i>>5)][i&31]
  const float* b_src = w1 + (size_t)(n0 + (lane & 31)) * KIN + kstart + (lane >> 5);
  const float* z_src = zbuf + lane;   // 256B zeroed region

  f32x2 acc[4][2];   // single panel chain: [mi][nj] covers cols 2nj,2nj+1
#pragma unroll
  for (int mi = 0; mi < 4; mi++)
#pragma unroll
    for (int nj = 0; nj < 2; nj++) acc[mi][nj] = (f32x2)(0.0f);

#define ISSUE(P, TILE, TAILF)                                             \
  {                                                                       \
    if (wv == 0) {                                                        \
      _Pragma("unroll")                                                   \
      for (int q = 0; q < 10; q++)                                        \
        gload4(a_base + aoff[q] + (size_t)(TILE) * BK, &As[P][64 * q]);   \
    } else if (wv == 1) {                                                 \
      _Pragma("unroll")                                                   \
      for (int q = 0; q < 8; q++) {                                       \
        const float* s = ((TAILF) && q >= 4) ? z_src                      \
                         : (b_src + (size_t)(TILE) * BK + 2 * q);         \
        gload4(s, &Bs[P][2 * q][0]);                                      \
      }                                                                   \
    }                                                                     \
  }

  // ---- prologue: stage tile 0 into buffer 0 ----
  ISSUE(0, 0, false)
  __syncthreads();   // issuing waves drain vmcnt before signaling

  int p = 0;
  for (int tile = 0; tile < ntile; tile++) {
    // issue next tile into the other buffer; lands while we compute
    if (tile + 1 < ntile) {
      const bool tf = htail && (tile + 1 == 16);
      ISSUE(p ^ 1, tile + 1, tf)
    }
    // ---- A fragment: 4 rows x 16 kk = 4x ds_read_b128 (bank-free) ----
    const u32* aw = &As[p][AGW * tm];
    uint4 q0 = *(const uint4*)(aw);       // row 4tm+0, kk 0..15
    uint4 q1 = *(const uint4*)(aw + 4);   // row 4tm+1
    uint4 q2 = *(const uint4*)(aw + 8);   // row 4tm+2
    uint4 q3 = *(const uint4*)(aw + 12);  // row 4tm+3
#pragma unroll
    for (int kk = 0; kk < BK; kk++) {
      const int c = kk >> 2, sh = kk & 3;
      const u32 r0 = (c == 0) ? q0.x : (c == 1) ? q0.y : (c == 2) ? q0.z : q0.w;
      const u32 r1 = (c == 0) ? q1.x : (c == 1) ? q1.y : (c == 2) ? q1.z : q1.w;
      const u32 r2 = (c == 0) ? q2.x : (c == 1) ? q2.y : (c == 2) ? q2.z : q2.w;
      const u32 r3 = (c == 0) ? q3.x : (c == 1) ? q3.y : (c == 2) ? q3.z : q3.w;
      f32x2 am[2];
      am[0].x = cvt_ub(r0, sh);  am[0].y = cvt_ub(r1, sh);
      am[1].x = cvt_ub(r2, sh);  am[1].y = cvt_ub(r3, sh);
      float4 bv = *(const float4*)&Bs[p][kk][tn * 4];
      f32x2 b2[2];
      b2[0].x = bv.x; b2[0].y = bv.y;
      b2[1].x = bv.z; b2[1].y = bv.w;
      // rows: mi = 2*mp + h (h = broadcast half of am[mp]); ascending-k chain
#pragma unroll
      for (int mp = 0; mp < 2; mp++) {
        pk_fma_lo(acc[2 * mp + 0][0], am[mp], b2[0]);
        pk_fma_lo(acc[2 * mp + 0][1], am[mp], b2[1]);
        pk_fma_hi(acc[2 * mp + 1][0], am[mp], b2[0]);
        pk_fma_hi(acc[2 * mp + 1][1], am[mp], b2[1]);
      }
    }
    __syncthreads();   // everyone done reading p; next-tile loads landed
    p ^= 1;
  }
#undef ISSUE

  // epilogue: write RAW panel partial (combine happens in update_kernel)
  float* base = gp + (size_t)panel * BSZ * HID;
#pragma unroll
  for (int mi = 0; mi < 4; mi++) {
    float* dst = base + (size_t)(m0 + tm * 4 + mi) * HID + n0 + tn * 4;
    float4 o;
    o.x = acc[mi][0].x;
    o.y = acc[mi][0].y;
    o.z = acc[mi][1].x;
    o.w = acc[mi][1].y;
    *(float4*)dst = o;
  }
}

// ---------------------------------------------------------------------------
// Kernel 3: combine panels (exact Eigen order) + membrane update + spike +
// mem2 accumulation.
// g = 0.5 * rn(rn(P0+P1) + P2)   (0.5 exact)
// m = rn(rn(0.95f*mem) + rn(0.05f*g)) — mul/mul/add; products NOT exact here,
// so FMA contraction would change bits — keep split __fmul_rn/__fadd_rn.
// ---------------------------------------------------------------------------
__global__ __launch_bounds__(256) void update_kernel(const float* __restrict__ gp,
                                                     float* __restrict__ mem1,
                                                     const float* __restrict__ w2,
                                                     float* __restrict__ mem2) {
  __shared__ float w2s[NOUT * HID];   // 32 KB
  for (int i = threadIdx.x; i < NOUT * HID; i += 256) w2s[i] = w2[i];
  __syncthreads();

  const int wave = threadIdx.x / 64;
  const int lane = threadIdx.x % 64;
  const int b = blockIdx.x * 4 + wave;

  const size_t GS = (size_t)BSZ * HID;
  const float* g0 = gp + (size_t)b * HID;
  const float* g1 = g0 + GS;
  const float* g2 = g1 + GS;
  float* mrow = mem1 + (size_t)b * HID;

  float acc[NOUT];
#pragma unroll
  for (int i = 0; i < NOUT; i++) acc[i] = 0.0f;

  for (int j = lane; j < HID; j += 64) {
    float gs = __fmul_rn(0.5f, __fadd_rn(__fadd_rn(g0[j], g1[j]), g2[j]));
    float m = __fadd_rn(__fmul_rn(0.95f, mrow[j]), __fmul_rn(0.05f, gs));
    bool spike = __fadd_rn(m, -1.0f) > 0.0f;
    mrow[j] = spike ? __fadd_rn(m, -1.0f) : m;
    if (spike) {
#pragma unroll
      for (int i = 0; i < NOUT; i++) acc[i] += w2s[i * HID + j];
    }
  }
  // mem2 never feeds back into spike decisions: reduction-order noise ~1e-7
  // << 3.6e-3 threshold, no need to replicate ref's order here.
#pragma unroll
  for (int i = 0; i < NOUT; i++) {
    float v = acc[i];
    for (int off = 32; off > 0; off >>= 1) v += __shfl_down(v, off);
    if (lane == 0) mem2[(size_t)b * NOUT + i] += v;
  }
}

// ---------------------------------------------------------------------------
// Kernel 4: out = mem2 / num_steps
// ---------------------------------------------------------------------------
__global__ __launch_bounds__(256) void finalize_kernel(const float* __restrict__ mem2,
                                                       const int* __restrict__ ns,
                                                       float* __restrict__ out) {
  int i = blockIdx.x * blockDim.x + threadIdx.x;
  if (i < BSZ * NOUT) out[i] = mem2[i] / (float)(*ns);
}

// ---------------------------------------------------------------------------
extern "C" void kernel_launch(void* const* d_in, const int* in_sizes, int n_in,
                              void* d_out, int out_size, void* d_ws, size_t ws_size,
                              hipStream_t stream) {
  const float* inp = (const float*)d_in[0];
  const float* w1  = (const float*)d_in[1];
  const float* w2  = (const float*)d_in[2];
  const int*   dns = (const int*)d_in[3];
  float* out = (float*)d_out;

  char* ws = (char*)d_ws;
  size_t off = 0;
  uint8_t* enc = (uint8_t*)(ws + off);  off += (size_t)BSZ * KIN;          // 6.4 MB
  off = (off + 255) & ~(size_t)255;
  float* gp   = (float*)(ws + off);     off += (size_t)3 * BSZ * HID * 4;  // 78.6 MB
  float* mem1 = (float*)(ws + off);     off += (size_t)BSZ * HID * 4;      // 26.2 MB
  float* mem2 = (float*)(ws + off);     off += (size_t)BSZ * NOUT * 4;     // 0.33 MB
  float* zbuf = (float*)(ws + off);     off += 256;                        // 256 B zeros

  (void)hipMemsetAsync(mem1, 0, (size_t)BSZ * HID * 4, stream);
  (void)hipMemsetAsync(mem2, 0, (size_t)BSZ * NOUT * 4, stream);
  (void)hipMemsetAsync(zbuf, 0, 256, stream);

  // Step keys: partitionable split — key_t = threefry((0,42), (0,t)).
  uint32_t keys[NSTEP][2];
  for (int t = 0; t < NSTEP; t++)
    threefry2x32(0u, 42u, 0u, (uint32_t)t, &keys[t][0], &keys[t][1]);

  const int n_elem = BSZ * KIN;
  for (int t = 0; t < NSTEP; t++) {
    enc_kernel<<<(n_elem + 255) / 256, 256, 0, stream>>>(inp, enc, keys[t][0], keys[t][1]);
    gemm_kernel<<<dim3(BSZ / BM, HID / BN, 3), 256, 0, stream>>>(enc, w1, zbuf, gp);
    update_kernel<<<BSZ / 4, 256, 0, stream>>>(gp, mem1, w2, mem2);
  }
  finalize_kernel<<<(BSZ * NOUT + 255) / 256, 256, 0, stream>>>(mem2, dns, out);
}